// Round 1
// baseline (232.826 us; speedup 1.0000x reference)
//
#include <hip/hip_runtime.h>
#include <hip/hip_bf16.h>

typedef __attribute__((ext_vector_type(8))) short short8;
typedef __attribute__((ext_vector_type(16))) float f32x16;

__device__ __forceinline__ float bf2f(unsigned short h){
  union{unsigned u; float f;} c; c.u = ((unsigned)h)<<16; return c.f;
}
__device__ __forceinline__ unsigned short f2bf(float f){
  union{float f; unsigned u;} c; c.f = f;
  return (unsigned short)((c.u + 0x7fffu + ((c.u>>16)&1u))>>16);
}

// ---- precompute combined weights: WcT[i][c][k] (transposed, bf16) ----
// k<96:  A[k][c] = sum_j W1[i][k][j] * W2[i][j][c]
// k>=96: B[k'][c] = sum_j W0[i][k'][j] * W2[i][96+j][c]
__global__ void k_wc(const float* __restrict__ W0, const float* __restrict__ W1,
                     const float* __restrict__ W2, unsigned short* __restrict__ WcT){
  int b = blockIdx.x;
  int i = b / 192, k = b % 192, c = threadIdx.x;   // 96 threads
  const float* w2 = W2 + (size_t)i*192*96;
  float s = 0.f;
  if (k < 96){
    const float* w1 = W1 + (size_t)i*96*96 + (size_t)k*96;
    for (int j=0;j<96;++j) s += w1[j] * w2[j*96 + c];
  } else {
    const float* w0 = W0 + (size_t)i*96*96 + (size_t)(k-96)*96;
    for (int j=0;j<96;++j) s += w0[j] * w2[(96+j)*96 + c];
  }
  WcT[(size_t)i*96*192 + (size_t)c*192 + k] = f2bf(s);
}

// cvec[i][c] = b1[i]@W2_top[:,c] + b2[i][c] ; dvec[i][c] = b0[i]@W2_bot[:,c]
__global__ void k_bias(const float* __restrict__ b0, const float* __restrict__ b1,
                       const float* __restrict__ b2, const float* __restrict__ W2,
                       float* __restrict__ cvec, float* __restrict__ dvec){
  int i = blockIdx.x, c = threadIdx.x;
  const float* w2 = W2 + (size_t)i*192*96;
  float s = b2[i*96+c], d = 0.f;
  for (int j=0;j<96;++j){
    s += b1[i*96+j] * w2[j*96 + c];
    d += b0[i*96+j] * w2[(96+j)*96 + c];
  }
  cvec[i*96+c] = s; dvec[i*96+c] = d;
}

__global__ void k_cast(const float* __restrict__ x, unsigned short* __restrict__ xb, int total4){
  int idx = blockIdx.x*blockDim.x + threadIdx.x;
  if (idx >= total4) return;
  float4 v = reinterpret_cast<const float4*>(x)[idx];
  ushort4 o; o.x = f2bf(v.x); o.y = f2bf(v.y); o.z = f2bf(v.z); o.w = f2bf(v.w);
  reinterpret_cast<ushort4*>(xb)[idx] = o;
}

__global__ void k_rowptr(const int* __restrict__ dst, int nE, int* __restrict__ rs, int nN){
  int n = blockIdx.x*blockDim.x + threadIdx.x;
  if (n > nN) return;
  int lo = 0, hi = nE;
  while (lo < hi){ int mid = (lo+hi)>>1; if (dst[mid] < n) lo = mid+1; else hi = mid; }
  rs[n] = lo;
}

__global__ void k_deg(const int* __restrict__ rs, int* __restrict__ deg, int nN){
  int n = blockIdx.x*blockDim.x + threadIdx.x;
  if (n >= nN) return;
  deg[n] = rs[n+1] - rs[n];
}

// xa[n] = sum over in-edges of x_bf16[src]; blockDim=(24,8): 24 col-quads x 8 nodes
__global__ void k_agg(const unsigned short* __restrict__ xb, const int* __restrict__ esrc,
                      const int* __restrict__ rs, unsigned short* __restrict__ xa, int nN){
  int n = blockIdx.x*blockDim.y + threadIdx.y;
  if (n >= nN) return;
  int q = threadIdx.x;                       // 0..23, 4 bf16 cols each
  int e0 = rs[n], e1 = rs[n+1];
  float a0=0.f, a1=0.f, a2=0.f, a3=0.f;
  for (int e=e0; e<e1; ++e){
    int s = esrc[e];
    uint2 w = *reinterpret_cast<const uint2*>(xb + (size_t)s*96 + q*4);
    a0 += bf2f((unsigned short)(w.x & 0xffffu));
    a1 += bf2f((unsigned short)(w.x >> 16));
    a2 += bf2f((unsigned short)(w.y & 0xffffu));
    a3 += bf2f((unsigned short)(w.y >> 16));
  }
  uint2 o;
  o.x = (unsigned)f2bf(a0) | ((unsigned)f2bf(a1) << 16);
  o.y = (unsigned)f2bf(a2) | ((unsigned)f2bf(a3) << 16);
  *reinterpret_cast<uint2*>(xa + (size_t)n*96 + q*4) = o;
}

// out[row] = rownorm( x@A + xa@B + cvec + deg*dvec ); one wave = 32 rows x 96 cols
template<int LAST>
__global__ __launch_bounds__(256) void k_gemm(
    const unsigned short* __restrict__ xb, const unsigned short* __restrict__ xav,
    const unsigned short* __restrict__ WcT, const float* __restrict__ cvec,
    const float* __restrict__ dvec, const int* __restrict__ deg,
    float* __restrict__ outf, unsigned short* __restrict__ outb, int nN)
{
  const int wid = (blockIdx.x<<2) + (threadIdx.x>>6);
  const int nstrips = (nN+31)>>5;
  if (wid >= nstrips) return;
  const int lane = threadIdx.x & 63;
  const int cl = lane & 31;
  const int hf = lane >> 5;
  const int row0 = wid << 5;
  int arow = row0 + cl; if (arow >= nN) arow = nN-1;

  const short8* xr = reinterpret_cast<const short8*>(xb  + (size_t)arow*96);
  const short8* ar = reinterpret_cast<const short8*>(xav + (size_t)arow*96);

  // A fragments: lane holds row (lane&31), 8 contiguous k at offset kt*16 + hf*8
  short8 afr[12];
  #pragma unroll
  for (int kt=0; kt<6; ++kt){ afr[kt] = xr[kt*2 + hf]; afr[6+kt] = ar[kt*2 + hf]; }

  f32x16 acc[3];
  #pragma unroll
  for (int t=0;t<3;++t){
    #pragma unroll
    for (int i=0;i<16;++i) acc[t][i] = 0.f;
  }

  // B fragments straight from L2-resident WcT (row c = t*32+cl, same k map as A)
  #pragma unroll
  for (int kt=0; kt<12; ++kt){
    short8 a = afr[kt];
    #pragma unroll
    for (int t=0;t<3;++t){
      const short8* bp = reinterpret_cast<const short8*>(WcT + (size_t)(t*32+cl)*192);
      short8 b = bp[kt*2 + hf];          // k = kt*16 + hf*8 (xa part lands at +96 automatically)
      acc[t] = __builtin_amdgcn_mfma_f32_32x32x16_bf16(a, b, acc[t], 0, 0, 0);
    }
  }

  float cv[3], dv[3];
  #pragma unroll
  for (int t=0;t<3;++t){ cv[t] = cvec[t*32+cl]; dv[t] = dvec[t*32+cl]; }

  #pragma unroll
  for (int r=0;r<16;++r){
    const int rl = (r&3) + ((r>>2)<<3) + (hf<<2);   // verified C/D row map
    const int rg = row0 + rl;
    const int rgc = rg < nN ? rg : nN-1;
    const float dgv = (float)deg[rgc];
    float v0 = acc[0][r] + cv[0] + dgv*dv[0];
    float v1 = acc[1][r] + cv[1] + dgv*dv[1];
    float v2 = acc[2][r] + cv[2] + dgv*dv[2];
    float s  = v0+v1+v2;
    float s2 = v0*v0 + v1*v1 + v2*v2;
    #pragma unroll
    for (int m=1;m<32;m<<=1){ s += __shfl_xor(s,m,64); s2 += __shfl_xor(s2,m,64); }
    float var = (s2 - s*s*(1.0f/96.0f)) * (1.0f/95.0f);   // ddof=1
    float sc  = 1.0f / sqrtf(var);
    if (rg < nN){
      if (LAST){
        float* o = outf + (size_t)rg*96;
        o[cl] = v0*sc; o[32+cl] = v1*sc; o[64+cl] = v2*sc;
      } else {
        unsigned short* o = outb + (size_t)rg*96;
        o[cl] = f2bf(v0*sc); o[32+cl] = f2bf(v1*sc); o[64+cl] = f2bf(v2*sc);
      }
    }
  }
}

extern "C" void kernel_launch(void* const* d_in, const int* in_sizes, int n_in,
                              void* d_out, int out_size, void* d_ws, size_t ws_size,
                              hipStream_t stream)
{
  const float* x   = (const float*)d_in[0];
  const float* W0  = (const float*)d_in[1];
  const float* b0  = (const float*)d_in[2];
  const float* W1  = (const float*)d_in[3];
  const float* b1  = (const float*)d_in[4];
  const float* W2  = (const float*)d_in[5];
  const float* b2  = (const float*)d_in[6];
  const int* esrc  = (const int*)d_in[7];
  const int* edst  = (const int*)d_in[8];
  const int nN = in_sizes[0] / 96;
  const int nE = in_sizes[7];
  const int depth = in_sizes[1] / (96*96);
  float* out = (float*)d_out;

  char* p = (char*)d_ws;
  auto alloc = [&](size_t bytes)->char*{ char* r = p; p += (bytes + 255) & ~(size_t)255; return r; };
  unsigned short* WcT  = (unsigned short*)alloc((size_t)depth*96*192*2);
  float* cvec          = (float*)alloc((size_t)depth*96*4);
  float* dvec          = (float*)alloc((size_t)depth*96*4);
  int* rs              = (int*)alloc((size_t)(nN+1)*4);
  int* deg             = (int*)alloc((size_t)nN*4);
  unsigned short* xb0  = (unsigned short*)alloc((size_t)nN*96*2);
  unsigned short* xb1  = (unsigned short*)alloc((size_t)nN*96*2);
  unsigned short* xav  = (unsigned short*)alloc((size_t)nN*96*2);

  k_wc<<<dim3(depth*192), dim3(96), 0, stream>>>(W0, W1, W2, WcT);
  k_bias<<<dim3(depth), dim3(96), 0, stream>>>(b0, b1, b2, W2, cvec, dvec);
  int tot4 = nN*96/4;
  k_cast<<<dim3((tot4+255)/256), dim3(256), 0, stream>>>(x, xb0, tot4);
  k_rowptr<<<dim3((nN+1+255)/256), dim3(256), 0, stream>>>(edst, nE, rs, nN);
  k_deg<<<dim3((nN+255)/256), dim3(256), 0, stream>>>(rs, deg, nN);

  const int aggGrid  = (nN+7)/8;
  const int gemmGrid = (((nN+31)/32)+3)/4;

  unsigned short* cur = xb0;
  unsigned short* nxt = xb1;
  for (int i=0; i<depth; ++i){
    k_agg<<<dim3(aggGrid), dim3(24,8), 0, stream>>>(cur, esrc, rs, xav, nN);
    if (i == depth-1){
      k_gemm<1><<<dim3(gemmGrid), dim3(256), 0, stream>>>(
          cur, xav, WcT + (size_t)i*96*192, cvec + i*96, dvec + i*96, deg,
          out, (unsigned short*)nullptr, nN);
    } else {
      k_gemm<0><<<dim3(gemmGrid), dim3(256), 0, stream>>>(
          cur, xav, WcT + (size_t)i*96*192, cvec + i*96, dvec + i*96, deg,
          (float*)nullptr, nxt, nN);
      unsigned short* t = cur; cur = nxt; nxt = t;
    }
  }
}

// Round 4
// 192.606 us; speedup vs baseline: 1.2088x; 1.2088x over previous
//
#include <hip/hip_runtime.h>
#include <hip/hip_bf16.h>

typedef __attribute__((ext_vector_type(8))) short short8;
typedef __attribute__((ext_vector_type(16))) float f32x16;

__device__ __forceinline__ float bf2f(unsigned short h){
  union{unsigned u; float f;} c; c.u = ((unsigned)h)<<16; return c.f;
}
__device__ __forceinline__ unsigned short f2bf(float f){
  union{float f; unsigned u;} c; c.f = f;
  return (unsigned short)((c.u + 0x7fffu + ((c.u>>16)&1u))>>16);
}

// ---- precompute combined weights: WcT[i][c][k] (transposed, bf16) ----
__global__ void k_wc(const float* __restrict__ W0, const float* __restrict__ W1,
                     const float* __restrict__ W2, unsigned short* __restrict__ WcT){
  int b = blockIdx.x;
  int i = b / 192, k = b % 192, c = threadIdx.x;   // 96 threads
  const float* w2 = W2 + (size_t)i*192*96;
  float s = 0.f;
  if (k < 96){
    const float* w1 = W1 + (size_t)i*96*96 + (size_t)k*96;
    for (int j=0;j<96;++j) s += w1[j] * w2[j*96 + c];
  } else {
    const float* w0 = W0 + (size_t)i*96*96 + (size_t)(k-96)*96;
    for (int j=0;j<96;++j) s += w0[j] * w2[(96+j)*96 + c];
  }
  WcT[(size_t)i*96*192 + (size_t)c*192 + k] = f2bf(s);
}

__global__ void k_bias(const float* __restrict__ b0, const float* __restrict__ b1,
                       const float* __restrict__ b2, const float* __restrict__ W2,
                       float* __restrict__ cvec, float* __restrict__ dvec){
  int i = blockIdx.x, c = threadIdx.x;
  const float* w2 = W2 + (size_t)i*192*96;
  float s = b2[i*96+c], d = 0.f;
  for (int j=0;j<96;++j){
    s += b1[i*96+j] * w2[j*96 + c];
    d += b0[i*96+j] * w2[(96+j)*96 + c];
  }
  cvec[i*96+c] = s; dvec[i*96+c] = d;
}

__global__ void k_cast(const float* __restrict__ x, unsigned short* __restrict__ xb, int total4){
  int idx = blockIdx.x*blockDim.x + threadIdx.x;
  if (idx >= total4) return;
  float4 v = reinterpret_cast<const float4*>(x)[idx];
  ushort4 o; o.x = f2bf(v.x); o.y = f2bf(v.y); o.z = f2bf(v.z); o.w = f2bf(v.w);
  reinterpret_cast<ushort4*>(xb)[idx] = o;
}

__global__ void k_rowptr(const int* __restrict__ dst, int nE, int* __restrict__ rs, int nN){
  int n = blockIdx.x*blockDim.x + threadIdx.x;
  if (n > nN) return;
  int lo = 0, hi = nE;
  while (lo < hi){ int mid = (lo+hi)>>1; if (dst[mid] < n) lo = mid+1; else hi = mid; }
  rs[n] = lo;
}

__device__ __forceinline__ void acc8(float* a, uint4 v){
  a[0] += bf2f((unsigned short)(v.x & 0xffffu));
  a[1] += bf2f((unsigned short)(v.x >> 16));
  a[2] += bf2f((unsigned short)(v.y & 0xffffu));
  a[3] += bf2f((unsigned short)(v.y >> 16));
  a[4] += bf2f((unsigned short)(v.z & 0xffffu));
  a[5] += bf2f((unsigned short)(v.z >> 16));
  a[6] += bf2f((unsigned short)(v.w & 0xffffu));
  a[7] += bf2f((unsigned short)(v.w >> 16));
}

// xa[n] = sum over in-edges of x_bf16[src]
// 12 threads/node x 16B each; 4-way edge unroll for MLP (memory-level parallelism).
// Also emits deg[n] (thread q==0).
__global__ __launch_bounds__(192) void k_agg(
    const unsigned short* __restrict__ xb, const int* __restrict__ esrc,
    const int* __restrict__ rs, unsigned short* __restrict__ xa,
    int* __restrict__ deg, int nN)
{
  int n = blockIdx.x*16 + threadIdx.y;
  if (n >= nN) return;
  const int q = threadIdx.x;                 // 0..11, 8 bf16 cols each
  const unsigned short* xq = xb + q*8;
  const int e0 = rs[n], e1 = rs[n+1];
  if (q == 0) deg[n] = e1 - e0;

  float a[8] = {0,0,0,0,0,0,0,0};

  int e = e0;
  for (; e+4 <= e1; e += 4){
    int s0 = esrc[e], s1 = esrc[e+1], s2 = esrc[e+2], s3 = esrc[e+3];
    uint4 v0 = *reinterpret_cast<const uint4*>(xq + (size_t)s0*96);
    uint4 v1 = *reinterpret_cast<const uint4*>(xq + (size_t)s1*96);
    uint4 v2 = *reinterpret_cast<const uint4*>(xq + (size_t)s2*96);
    uint4 v3 = *reinterpret_cast<const uint4*>(xq + (size_t)s3*96);
    acc8(a, v0); acc8(a, v1); acc8(a, v2); acc8(a, v3);
  }
  for (; e < e1; ++e){
    int s = esrc[e];
    uint4 v = *reinterpret_cast<const uint4*>(xq + (size_t)s*96);
    acc8(a, v);
  }

  uint4 o;
  o.x = (unsigned)f2bf(a[0]) | ((unsigned)f2bf(a[1]) << 16);
  o.y = (unsigned)f2bf(a[2]) | ((unsigned)f2bf(a[3]) << 16);
  o.z = (unsigned)f2bf(a[4]) | ((unsigned)f2bf(a[5]) << 16);
  o.w = (unsigned)f2bf(a[6]) | ((unsigned)f2bf(a[7]) << 16);
  *reinterpret_cast<uint4*>(xa + (size_t)n*96 + q*8) = o;
}

// out[row] = rownorm( x@A + xa@B + cvec + deg*dvec ); one wave = 32 rows x 96 cols
template<int LAST>
__global__ __launch_bounds__(256) void k_gemm(
    const unsigned short* __restrict__ xb, const unsigned short* __restrict__ xav,
    const unsigned short* __restrict__ WcT, const float* __restrict__ cvec,
    const float* __restrict__ dvec, const int* __restrict__ deg,
    float* __restrict__ outf, unsigned short* __restrict__ outb, int nN)
{
  const int wid = (blockIdx.x<<2) + (threadIdx.x>>6);
  const int nstrips = (nN+31)>>5;
  if (wid >= nstrips) return;
  const int lane = threadIdx.x & 63;
  const int cl = lane & 31;
  const int hf = lane >> 5;
  const int row0 = wid << 5;
  int arow = row0 + cl; if (arow >= nN) arow = nN-1;

  const short8* xr = reinterpret_cast<const short8*>(xb  + (size_t)arow*96);
  const short8* ar = reinterpret_cast<const short8*>(xav + (size_t)arow*96);

  short8 afr[12];
  #pragma unroll
  for (int kt=0; kt<6; ++kt){ afr[kt] = xr[kt*2 + hf]; afr[6+kt] = ar[kt*2 + hf]; }

  f32x16 acc[3];
  #pragma unroll
  for (int t=0;t<3;++t){
    #pragma unroll
    for (int i=0;i<16;++i) acc[t][i] = 0.f;
  }

  #pragma unroll
  for (int kt=0; kt<12; ++kt){
    short8 a = afr[kt];
    #pragma unroll
    for (int t=0;t<3;++t){
      const short8* bp = reinterpret_cast<const short8*>(WcT + (size_t)(t*32+cl)*192);
      short8 b = bp[kt*2 + hf];          // k = kt*16 + hf*8
      acc[t] = __builtin_amdgcn_mfma_f32_32x32x16_bf16(a, b, acc[t], 0, 0, 0);
    }
  }

  float cv[3], dv[3];
  #pragma unroll
  for (int t=0;t<3;++t){ cv[t] = cvec[t*32+cl]; dv[t] = dvec[t*32+cl]; }

  #pragma unroll
  for (int r=0;r<16;++r){
    const int rl = (r&3) + ((r>>2)<<3) + (hf<<2);   // verified C/D row map
    const int rg = row0 + rl;
    const int rgc = rg < nN ? rg : nN-1;
    const float dgv = (float)deg[rgc];
    float v0 = acc[0][r] + cv[0] + dgv*dv[0];
    float v1 = acc[1][r] + cv[1] + dgv*dv[1];
    float v2 = acc[2][r] + cv[2] + dgv*dv[2];
    float s  = v0+v1+v2;
    float s2 = v0*v0 + v1*v1 + v2*v2;
    #pragma unroll
    for (int m=1;m<32;m<<=1){ s += __shfl_xor(s,m,64); s2 += __shfl_xor(s2,m,64); }
    float var = (s2 - s*s*(1.0f/96.0f)) * (1.0f/95.0f);   // ddof=1
    float sc  = 1.0f / sqrtf(var);
    if (rg < nN){
      if (LAST){
        float* o = outf + (size_t)rg*96;
        o[cl] = v0*sc; o[32+cl] = v1*sc; o[64+cl] = v2*sc;
      } else {
        unsigned short* o = outb + (size_t)rg*96;
        o[cl] = f2bf(v0*sc); o[32+cl] = f2bf(v1*sc); o[64+cl] = f2bf(v2*sc);
      }
    }
  }
}

extern "C" void kernel_launch(void* const* d_in, const int* in_sizes, int n_in,
                              void* d_out, int out_size, void* d_ws, size_t ws_size,
                              hipStream_t stream)
{
  const float* x   = (const float*)d_in[0];
  const float* W0  = (const float*)d_in[1];
  const float* b0  = (const float*)d_in[2];
  const float* W1  = (const float*)d_in[3];
  const float* b1  = (const float*)d_in[4];
  const float* W2  = (const float*)d_in[5];
  const float* b2  = (const float*)d_in[6];
  const int* esrc  = (const int*)d_in[7];
  const int* edst  = (const int*)d_in[8];
  const int nN = in_sizes[0] / 96;
  const int nE = in_sizes[7];
  const int depth = in_sizes[1] / (96*96);
  float* out = (float*)d_out;

  char* p = (char*)d_ws;
  auto alloc = [&](size_t bytes)->char*{ char* r = p; p += (bytes + 255) & ~(size_t)255; return r; };
  unsigned short* WcT  = (unsigned short*)alloc((size_t)depth*96*192*2);
  float* cvec          = (float*)alloc((size_t)depth*96*4);
  float* dvec          = (float*)alloc((size_t)depth*96*4);
  int* rs              = (int*)alloc((size_t)(nN+1)*4);
  int* deg             = (int*)alloc((size_t)nN*4);
  unsigned short* xb0  = (unsigned short*)alloc((size_t)nN*96*2);
  unsigned short* xb1  = (unsigned short*)alloc((size_t)nN*96*2);
  unsigned short* xav  = (unsigned short*)alloc((size_t)nN*96*2);

  k_wc<<<dim3(depth*192), dim3(96), 0, stream>>>(W0, W1, W2, WcT);
  k_bias<<<dim3(depth), dim3(96), 0, stream>>>(b0, b1, b2, W2, cvec, dvec);
  int tot4 = nN*96/4;
  k_cast<<<dim3((tot4+255)/256), dim3(256), 0, stream>>>(x, xb0, tot4);
  k_rowptr<<<dim3((nN+1+255)/256), dim3(256), 0, stream>>>(edst, nE, rs, nN);

  const int aggGrid  = (nN+15)/16;
  const int gemmGrid = (((nN+31)/32)+3)/4;

  unsigned short* cur = xb0;
  unsigned short* nxt = xb1;
  for (int i=0; i<depth; ++i){
    k_agg<<<dim3(aggGrid), dim3(12,16), 0, stream>>>(cur, esrc, rs, xav, deg, nN);
    if (i == depth-1){
      k_gemm<1><<<dim3(gemmGrid), dim3(256), 0, stream>>>(
          cur, xav, WcT + (size_t)i*96*192, cvec + i*96, dvec + i*96, deg,
          out, (unsigned short*)nullptr, nN);
    } else {
      k_gemm<0><<<dim3(gemmGrid), dim3(256), 0, stream>>>(
          cur, xav, WcT + (size_t)i*96*192, cvec + i*96, dvec + i*96, deg,
          (float*)nullptr, nxt, nN);
      unsigned short* t = cur; cur = nxt; nxt = t;
    }
  }
}

// Round 5
// 183.284 us; speedup vs baseline: 1.2703x; 1.0509x over previous
//
#include <hip/hip_runtime.h>
#include <hip/hip_bf16.h>

typedef __attribute__((ext_vector_type(8))) short short8;
typedef __attribute__((ext_vector_type(16))) float f32x16;

__device__ __forceinline__ float bf2f(unsigned short h){
  union{unsigned u; float f;} c; c.u = ((unsigned)h)<<16; return c.f;
}
__device__ __forceinline__ unsigned short f2bf(float f){
  union{float f; unsigned u;} c; c.f = f;
  return (unsigned short)((c.u + 0x7fffu + ((c.u>>16)&1u))>>16);
}

// ---- combined weights, fragment-major:
// WcF[((i*12+kt)*3+t)*512 + lane*8 + j] = Wc[k][c],
//   k = kt*16 + (lane>>5)*8 + j   (192-dim: 0..95 self, 96..191 agg)
//   c = t*32 + (lane&31)
// k<96:  Wc[k][c] = sum_j W1[i][k][j] * W2[i][j][c]
// k>=96: Wc[k][c] = sum_j W0[i][k-96][j] * W2[i][96+j][c]
__global__ void k_wc(const float* __restrict__ W0, const float* __restrict__ W1,
                     const float* __restrict__ W2, unsigned short* __restrict__ WcF){
  int b = blockIdx.x;
  int i = b / 192, k = b % 192, c = threadIdx.x;   // 96 threads
  const float* w2 = W2 + (size_t)i*192*96;
  float s = 0.f;
  if (k < 96){
    const float* w1 = W1 + (size_t)i*96*96 + (size_t)k*96;
    for (int j=0;j<96;++j) s += w1[j] * w2[j*96 + c];
  } else {
    const float* w0 = W0 + (size_t)i*96*96 + (size_t)(k-96)*96;
    for (int j=0;j<96;++j) s += w0[j] * w2[(96+j)*96 + c];
  }
  int kt = k >> 4, hfk = (k >> 3) & 1, j = k & 7;
  int t = c >> 5, cl = c & 31;
  WcF[(size_t)((i*12 + kt)*3 + t)*512 + (size_t)(hfk*32 + cl)*8 + j] = f2bf(s);
}

__global__ void k_bias(const float* __restrict__ b0, const float* __restrict__ b1,
                       const float* __restrict__ b2, const float* __restrict__ W2,
                       float* __restrict__ cvec, float* __restrict__ dvec){
  int i = blockIdx.x, c = threadIdx.x;
  const float* w2 = W2 + (size_t)i*192*96;
  float s = b2[i*96+c], d = 0.f;
  for (int j=0;j<96;++j){
    s += b1[i*96+j] * w2[j*96 + c];
    d += b0[i*96+j] * w2[(96+j)*96 + c];
  }
  cvec[i*96+c] = s; dvec[i*96+c] = d;
}

__global__ void k_cast(const float* __restrict__ x, unsigned short* __restrict__ xb, int total4){
  int idx = blockIdx.x*blockDim.x + threadIdx.x;
  if (idx >= total4) return;
  float4 v = reinterpret_cast<const float4*>(x)[idx];
  ushort4 o; o.x = f2bf(v.x); o.y = f2bf(v.y); o.z = f2bf(v.z); o.w = f2bf(v.w);
  reinterpret_cast<ushort4*>(xb)[idx] = o;
}

__global__ void k_rowptr(const int* __restrict__ dst, int nE, int* __restrict__ rs, int nN){
  int n = blockIdx.x*blockDim.x + threadIdx.x;
  if (n > nN) return;
  int lo = 0, hi = nE;
  while (lo < hi){ int mid = (lo+hi)>>1; if (dst[mid] < n) lo = mid+1; else hi = mid; }
  rs[n] = lo;
}

__device__ __forceinline__ void acc8(float* a, uint4 v){
  a[0] += bf2f((unsigned short)(v.x & 0xffffu));
  a[1] += bf2f((unsigned short)(v.x >> 16));
  a[2] += bf2f((unsigned short)(v.y & 0xffffu));
  a[3] += bf2f((unsigned short)(v.y >> 16));
  a[4] += bf2f((unsigned short)(v.z & 0xffffu));
  a[5] += bf2f((unsigned short)(v.z >> 16));
  a[6] += bf2f((unsigned short)(v.w & 0xffffu));
  a[7] += bf2f((unsigned short)(v.w >> 16));
}

// xa[n] = sum over in-edges of x_bf16[src]
// 12 threads/node x 16B; 8-way edge unroll for memory-level parallelism.
__global__ __launch_bounds__(192) void k_agg(
    const unsigned short* __restrict__ xb, const int* __restrict__ esrc,
    const int* __restrict__ rs, unsigned short* __restrict__ xa,
    int* __restrict__ deg, int nN)
{
  int n = blockIdx.x*16 + threadIdx.y;
  if (n >= nN) return;
  const int q = threadIdx.x;                 // 0..11, 8 bf16 cols each
  const unsigned short* xq = xb + q*8;
  const int e0 = rs[n], e1 = rs[n+1];
  if (q == 0) deg[n] = e1 - e0;

  float a[8] = {0,0,0,0,0,0,0,0};

  int e = e0;
  for (; e+8 <= e1; e += 8){
    int s0 = esrc[e],   s1 = esrc[e+1], s2 = esrc[e+2], s3 = esrc[e+3];
    int s4 = esrc[e+4], s5 = esrc[e+5], s6 = esrc[e+6], s7 = esrc[e+7];
    uint4 v0 = *reinterpret_cast<const uint4*>(xq + (size_t)s0*96);
    uint4 v1 = *reinterpret_cast<const uint4*>(xq + (size_t)s1*96);
    uint4 v2 = *reinterpret_cast<const uint4*>(xq + (size_t)s2*96);
    uint4 v3 = *reinterpret_cast<const uint4*>(xq + (size_t)s3*96);
    uint4 v4 = *reinterpret_cast<const uint4*>(xq + (size_t)s4*96);
    uint4 v5 = *reinterpret_cast<const uint4*>(xq + (size_t)s5*96);
    uint4 v6 = *reinterpret_cast<const uint4*>(xq + (size_t)s6*96);
    uint4 v7 = *reinterpret_cast<const uint4*>(xq + (size_t)s7*96);
    acc8(a, v0); acc8(a, v1); acc8(a, v2); acc8(a, v3);
    acc8(a, v4); acc8(a, v5); acc8(a, v6); acc8(a, v7);
  }
  for (; e+4 <= e1; e += 4){
    int s0 = esrc[e], s1 = esrc[e+1], s2 = esrc[e+2], s3 = esrc[e+3];
    uint4 v0 = *reinterpret_cast<const uint4*>(xq + (size_t)s0*96);
    uint4 v1 = *reinterpret_cast<const uint4*>(xq + (size_t)s1*96);
    uint4 v2 = *reinterpret_cast<const uint4*>(xq + (size_t)s2*96);
    uint4 v3 = *reinterpret_cast<const uint4*>(xq + (size_t)s3*96);
    acc8(a, v0); acc8(a, v1); acc8(a, v2); acc8(a, v3);
  }
  for (; e < e1; ++e){
    int s = esrc[e];
    uint4 v = *reinterpret_cast<const uint4*>(xq + (size_t)s*96);
    acc8(a, v);
  }

  uint4 o;
  o.x = (unsigned)f2bf(a[0]) | ((unsigned)f2bf(a[1]) << 16);
  o.y = (unsigned)f2bf(a[2]) | ((unsigned)f2bf(a[3]) << 16);
  o.z = (unsigned)f2bf(a[4]) | ((unsigned)f2bf(a[5]) << 16);
  o.w = (unsigned)f2bf(a[6]) | ((unsigned)f2bf(a[7]) << 16);
  *reinterpret_cast<uint4*>(xa + (size_t)n*96 + q*8) = o;
}

// out[row] = rownorm( x@A + xa@B + cvec + deg*dvec ); one wave = 32 rows x 96 cols
// B loads fully coalesced from fragment-major WcF (1KB per wave-load).
template<int LAST>
__global__ __launch_bounds__(256) void k_gemm(
    const unsigned short* __restrict__ xb, const unsigned short* __restrict__ xav,
    const unsigned short* __restrict__ WcF, const float* __restrict__ cvec,
    const float* __restrict__ dvec, const int* __restrict__ deg,
    float* __restrict__ outf, unsigned short* __restrict__ outb, int nN)
{
  const int wid = (blockIdx.x<<2) + (threadIdx.x>>6);
  const int nstrips = (nN+31)>>5;
  if (wid >= nstrips) return;
  const int lane = threadIdx.x & 63;
  const int cl = lane & 31;
  const int hf = lane >> 5;
  const int row0 = wid << 5;
  int arow = row0 + cl; if (arow >= nN) arow = nN-1;

  const short8* xr = reinterpret_cast<const short8*>(xb  + (size_t)arow*96);
  const short8* ar = reinterpret_cast<const short8*>(xav + (size_t)arow*96);
  const short8* wf = reinterpret_cast<const short8*>(WcF);

  short8 afr[12];
  #pragma unroll
  for (int kt=0; kt<6; ++kt){ afr[kt] = xr[kt*2 + hf]; afr[6+kt] = ar[kt*2 + hf]; }

  f32x16 acc[3];
  #pragma unroll
  for (int t=0;t<3;++t){
    #pragma unroll
    for (int i=0;i<16;++i) acc[t][i] = 0.f;
  }

  #pragma unroll
  for (int kt=0; kt<12; ++kt){
    short8 a = afr[kt];
    #pragma unroll
    for (int t=0;t<3;++t){
      short8 b = wf[(kt*3+t)*64 + lane];   // coalesced: wave covers contiguous 1KB
      acc[t] = __builtin_amdgcn_mfma_f32_32x32x16_bf16(a, b, acc[t], 0, 0, 0);
    }
  }

  float cv[3], dv[3];
  #pragma unroll
  for (int t=0;t<3;++t){ cv[t] = cvec[t*32+cl]; dv[t] = dvec[t*32+cl]; }

  #pragma unroll
  for (int r=0;r<16;++r){
    const int rl = (r&3) + ((r>>2)<<3) + (hf<<2);   // verified C/D row map
    const int rg = row0 + rl;
    const int rgc = rg < nN ? rg : nN-1;
    const float dgv = (float)deg[rgc];
    float v0 = acc[0][r] + cv[0] + dgv*dv[0];
    float v1 = acc[1][r] + cv[1] + dgv*dv[1];
    float v2 = acc[2][r] + cv[2] + dgv*dv[2];
    float s  = v0+v1+v2;
    float s2 = v0*v0 + v1*v1 + v2*v2;
    #pragma unroll
    for (int m=1;m<32;m<<=1){ s += __shfl_xor(s,m,64); s2 += __shfl_xor(s2,m,64); }
    float var = (s2 - s*s*(1.0f/96.0f)) * (1.0f/95.0f);   // ddof=1
    float sc  = 1.0f / sqrtf(var);
    if (rg < nN){
      if (LAST){
        float* o = outf + (size_t)rg*96;
        o[cl] = v0*sc; o[32+cl] = v1*sc; o[64+cl] = v2*sc;
      } else {
        unsigned short* o = outb + (size_t)rg*96;
        o[cl] = f2bf(v0*sc); o[32+cl] = f2bf(v1*sc); o[64+cl] = f2bf(v2*sc);
      }
    }
  }
}

extern "C" void kernel_launch(void* const* d_in, const int* in_sizes, int n_in,
                              void* d_out, int out_size, void* d_ws, size_t ws_size,
                              hipStream_t stream)
{
  const float* x   = (const float*)d_in[0];
  const float* W0  = (const float*)d_in[1];
  const float* b0  = (const float*)d_in[2];
  const float* W1  = (const float*)d_in[3];
  const float* b1  = (const float*)d_in[4];
  const float* W2  = (const float*)d_in[5];
  const float* b2  = (const float*)d_in[6];
  const int* esrc  = (const int*)d_in[7];
  const int* edst  = (const int*)d_in[8];
  const int nN = in_sizes[0] / 96;
  const int nE = in_sizes[7];
  const int depth = in_sizes[1] / (96*96);
  float* out = (float*)d_out;

  char* p = (char*)d_ws;
  auto alloc = [&](size_t bytes)->char*{ char* r = p; p += (bytes + 255) & ~(size_t)255; return r; };
  unsigned short* WcF  = (unsigned short*)alloc((size_t)depth*12*3*512*2);
  float* cvec          = (float*)alloc((size_t)depth*96*4);
  float* dvec          = (float*)alloc((size_t)depth*96*4);
  int* rs              = (int*)alloc((size_t)(nN+1)*4);
  int* deg             = (int*)alloc((size_t)nN*4);
  unsigned short* xb0  = (unsigned short*)alloc((size_t)nN*96*2);
  unsigned short* xb1  = (unsigned short*)alloc((size_t)nN*96*2);
  unsigned short* xav  = (unsigned short*)alloc((size_t)nN*96*2);

  k_wc<<<dim3(depth*192), dim3(96), 0, stream>>>(W0, W1, W2, WcF);
  k_bias<<<dim3(depth), dim3(96), 0, stream>>>(b0, b1, b2, W2, cvec, dvec);
  int tot4 = nN*96/4;
  k_cast<<<dim3((tot4+255)/256), dim3(256), 0, stream>>>(x, xb0, tot4);
  k_rowptr<<<dim3((nN+1+255)/256), dim3(256), 0, stream>>>(edst, nE, rs, nN);

  const int aggGrid  = (nN+15)/16;
  const int gemmGrid = (((nN+31)/32)+3)/4;

  unsigned short* cur = xb0;
  unsigned short* nxt = xb1;
  for (int i=0; i<depth; ++i){
    k_agg<<<dim3(aggGrid), dim3(12,16), 0, stream>>>(cur, esrc, rs, xav, deg, nN);
    if (i == depth-1){
      k_gemm<1><<<dim3(gemmGrid), dim3(256), 0, stream>>>(
          cur, xav, WcF + (size_t)i*12*3*512, cvec + i*96, dvec + i*96, deg,
          out, (unsigned short*)nullptr, nN);
    } else {
      k_gemm<0><<<dim3(gemmGrid), dim3(256), 0, stream>>>(
          cur, xav, WcF + (size_t)i*12*3*512, cvec + i*96, dvec + i*96, deg,
          (float*)nullptr, nxt, nN);
      unsigned short* t = cur; cur = nxt; nxt = t;
    }
  }
}